// Round 9
// baseline (109.376 us; speedup 1.0000x reference)
//
#include <hip/hip_runtime.h>
#include <hip/hip_bf16.h>

#define NB 4
#define NN 2048
#define NF 256
#define LOG2E 1.4426950408889634f

using bf16x8 = __attribute__((ext_vector_type(8))) short;
using f32x4  = __attribute__((ext_vector_type(4))) float;

__device__ __forceinline__ short f2bf(float f) {
    unsigned u = __float_as_uint(f);
    u += 0x7fffu + ((u >> 16) & 1u);   // RNE, finite inputs only
    return (short)(u >> 16);
}
__device__ __forceinline__ unsigned enc_ord(float f) {
    unsigned u = __float_as_uint(f);
    return (u & 0x80000000u) ? ~u : (u | 0x80000000u);
}
__device__ __forceinline__ float dec_ord(unsigned u) {
    unsigned i = (u & 0x80000000u) ? (u & 0x7fffffffu) : ~u;
    return __uint_as_float(i);
}

// ---- pack: adj -> 1-bit mask (ushort per 16), W->W^T bf16, maxfd init ----
__global__ __launch_bounds__(256) void pack_kernel(
    const int* __restrict__ adj, unsigned short* __restrict__ adjB16,
    const float* __restrict__ W, short* __restrict__ WT, unsigned* __restrict__ maxfd)
{
    const int blk = blockIdx.x, tid = threadIdx.x;
    if (blk < 4096) {                       // 1M threads x 16 ints (64 B each)
        const int g = blk*256 + tid;
        const int4* p = (const int4*)(adj + (size_t)g*16);
        int4 v0 = p[0], v1 = p[1], v2 = p[2], v3 = p[3];
        unsigned m = 0;
        m |= (v0.x>0)<<0;  m |= (v0.y>0)<<1;  m |= (v0.z>0)<<2;  m |= (v0.w>0)<<3;
        m |= (v1.x>0)<<4;  m |= (v1.y>0)<<5;  m |= (v1.z>0)<<6;  m |= (v1.w>0)<<7;
        m |= (v2.x>0)<<8;  m |= (v2.y>0)<<9;  m |= (v2.z>0)<<10; m |= (v2.w>0)<<11;
        m |= (v3.x>0)<<12; m |= (v3.y>0)<<13; m |= (v3.z>0)<<14; m |= (v3.w>0)<<15;
        adjB16[g] = (unsigned short)m;
    } else if (blk < 4096 + (NF*NF)/256) {
        int t = (blk - 4096)*256 + tid;
        WT[t] = f2bf(W[(t & 255)*NF + (t >> 8)]);   // WT[g][f] = W[f][g]
    } else if (tid < NB) {
        maxfd[tid] = 0u;
    }
}

// ---- h = x@W (bf16 MFMA, K-pipelined); hT[b][g][i], fs2/fd2 (x LOG2E), maxfd ----
__global__ __launch_bounds__(256,4) void h_kernel(
    const float* __restrict__ x, const short* __restrict__ WT, const float* __restrict__ a,
    short* __restrict__ hT, float* __restrict__ fs2, float* __restrict__ fd2,
    unsigned* __restrict__ maxfd)
{
    __shared__ float fs_l[16], fd_l[16];
    const int w  = threadIdx.x >> 6;
    const int l  = threadIdx.x & 63;
    const int lr = l & 15, lg = l >> 4;
    const int b  = blockIdx.x >> 7;
    const int ib = (blockIdx.x & 127) * 16;

    if (threadIdx.x < 16) { fs_l[threadIdx.x] = 0.f; fd_l[threadIdx.x] = 0.f; }
    __syncthreads();

    f32x4 acc[4];
    #pragma unroll
    for (int t = 0; t < 4; t++) acc[t] = (f32x4){0.f,0.f,0.f,0.f};

    const float* xrow = x + (size_t)(b*NN + ib + lr) * NF + 8*lg;
    const short* wtp  = WT + (size_t)(w*64 + lr) * NF + 8*lg;

    float4 xa[2][2]; bf16x8 bfr[2][4];
    xa[0][0] = *(const float4*)(xrow);
    xa[0][1] = *(const float4*)(xrow + 4);
    #pragma unroll
    for (int nt = 0; nt < 4; nt++) bfr[0][nt] = *(const bf16x8*)(wtp + nt*16*NF);

    #pragma unroll
    for (int ks = 0; ks < 8; ks++) {
        const int cur = ks & 1;
        if (ks < 7) {
            const int nxt = cur ^ 1;
            xa[nxt][0] = *(const float4*)(xrow + (ks+1)*32);
            xa[nxt][1] = *(const float4*)(xrow + (ks+1)*32 + 4);
            #pragma unroll
            for (int nt = 0; nt < 4; nt++)
                bfr[nxt][nt] = *(const bf16x8*)(wtp + nt*16*NF + (ks+1)*32);
        }
        bf16x8 af;
        af[0]=f2bf(xa[cur][0].x); af[1]=f2bf(xa[cur][0].y);
        af[2]=f2bf(xa[cur][0].z); af[3]=f2bf(xa[cur][0].w);
        af[4]=f2bf(xa[cur][1].x); af[5]=f2bf(xa[cur][1].y);
        af[6]=f2bf(xa[cur][1].z); af[7]=f2bf(xa[cur][1].w);
        #pragma unroll
        for (int nt = 0; nt < 4; nt++)
            acc[nt] = __builtin_amdgcn_mfma_f32_16x16x32_bf16(af, bfr[cur][nt], acc[nt], 0, 0, 0);
    }

    float fsv[4] = {0,0,0,0}, fdv[4] = {0,0,0,0};
    #pragma unroll
    for (int nt = 0; nt < 4; nt++) {
        int g = w*64 + nt*16 + lr;
        float as = a[g], ad = a[NF + g];
        short4 hv;
        hv.x = f2bf(acc[nt][0]); hv.y = f2bf(acc[nt][1]);
        hv.z = f2bf(acc[nt][2]); hv.w = f2bf(acc[nt][3]);
        *(short4*)(hT + ((size_t)(b*NF + g))*NN + ib + lg*4) = hv;
        #pragma unroll
        for (int r = 0; r < 4; r++) { fsv[r] += acc[nt][r]*as; fdv[r] += acc[nt][r]*ad; }
    }
    #pragma unroll
    for (int mask = 1; mask < 16; mask <<= 1) {
        #pragma unroll
        for (int r = 0; r < 4; r++) {
            fsv[r] += __shfl_xor(fsv[r], mask);
            fdv[r] += __shfl_xor(fdv[r], mask);
        }
    }
    if (lr == 0) {
        #pragma unroll
        for (int r = 0; r < 4; r++) {
            atomicAdd(&fs_l[lg*4 + r], fsv[r]);
            atomicAdd(&fd_l[lg*4 + r], fdv[r]);
        }
    }
    __syncthreads();
    if (threadIdx.x < 16) {
        float fsu = fs_l[threadIdx.x] * LOG2E;
        float fdu = fd_l[threadIdx.x] * LOG2E;
        fs2[b*NN + ib + threadIdx.x] = fsu;
        fd2[b*NN + ib + threadIdx.x] = fdu;
        float wm = fdu;
        #pragma unroll
        for (int m = 1; m < 16; m <<= 1) wm = fmaxf(wm, __shfl_xor(wm, m));
        if (threadIdx.x == 0) atomicMax(maxfd + b, enc_ord(wm));
    }
}

// ---- fused: masked softmax + att@h + elu — BARRIER-FREE main loop ----
// grid 512 = 4b x 64 itile(32 rows) x 2 fh(128 f); 512 thr = 8 waves
// = 2 rowg(16 rows) x 4 kt(512-j slice). 16 steps x 32 j per wave.
// No LDS/barriers in loop: P in-register (exp2+cvt_pk), B-frags L2->VGPR
// direct (8 indep loads/step, unroll-2 => register double-buffering).
// Epilogue: kt-tree via LDS (stride 132, conflict-free).
__global__ __launch_bounds__(512,2) void gat_fused(
    const short* __restrict__ hT, const unsigned char* __restrict__ adjB,
    const float* __restrict__ fs2, const float* __restrict__ fd2,
    const unsigned* __restrict__ maxfd, float* __restrict__ out)
{
    __shared__ float red[2][32*132];
    __shared__ float ls[32][4];

    const int tid = threadIdx.x;
    const int w = tid >> 6, l = tid & 63, lr = l & 15, lg = l >> 4;
    const int kt = w & 3, rowg = w >> 2;
    const int blk = blockIdx.x;
    const int b = blk >> 7, rest = blk & 127;
    const int itile = rest >> 1, fh = rest & 1;
    const int i0 = itile * 32, f0 = fh * 128;

    const short* hTb = hT + ((size_t)b * NF + f0) * NN;

    // per-row softmax constants (row = i0 + rowg*16 + lr), log2-scaled
    const float mx2 = dec_ord(maxfd[b]);
    const int girow = b*NN + i0 + rowg*16 + lr;
    const float fsv_ = fs2[girow];
    const float M = fmaxf(fsv_ + mx2, 0.f);
    const float fsM = fsv_ - M, nM = -M;

    const unsigned char* ar = adjB + (size_t)girow * (NN/8) + kt*64 + lg;
    const float* fdp = fd2 + b*NN + kt*512 + lg*8;

    // 8 per-nt base pointers (f-row = f0 + nt*16 + lr, j-slice base)
    const short* bp[8];
    #pragma unroll
    for (int nt = 0; nt < 8; ++nt)
        bp[nt] = hTb + (size_t)(nt*16 + lr) * NN + kt*512 + lg*8;

    f32x4 acc[8];
    #pragma unroll
    for (int nt = 0; nt < 8; ++nt) acc[nt] = (f32x4){0.f,0.f,0.f,0.f};
    float lsum = 0.f;

    #pragma unroll 2
    for (int t = 0; t < 16; ++t) {
        bf16x8 Bf[8];
        #pragma unroll
        for (int nt = 0; nt < 8; ++nt)
            Bf[nt] = *(const bf16x8*)(bp[nt] + t*32);
        const unsigned mb = ar[t*4];
        const f32x4 fa = *(const f32x4*)(fdp + t*32);
        const f32x4 fb = *(const f32x4*)(fdp + t*32 + 4);
        float fdv[8] = {fa[0],fa[1],fa[2],fa[3],fb[0],fb[1],fb[2],fb[3]};
        float p[8];
        #pragma unroll
        for (int e = 0; e < 8; ++e) {
            float v = __builtin_amdgcn_exp2f(fmaxf(fsM + fdv[e], nM));
            v = (mb & (1u << e)) ? v : 0.f;
            lsum += v;
            p[e] = v;
        }
        union { bf16x8 v; unsigned u[4]; } au;
        #pragma unroll
        for (int d = 0; d < 4; ++d)
            asm("v_cvt_pk_bf16_f32 %0, %1, %2" : "=v"(au.u[d]) : "v"(p[2*d]), "v"(p[2*d+1]));
        #pragma unroll
        for (int nt = 0; nt < 8; ++nt)
            acc[nt] = __builtin_amdgcn_mfma_f32_16x16x32_bf16(au.v, Bf[nt], acc[nt], 0, 0, 0);
    }

    // ---- epilogue: row sums + kt-tree reduction + elu + store ----
    lsum += __shfl_xor(lsum, 16);
    lsum += __shfl_xor(lsum, 32);
    if (l < 16) ls[rowg*16 + lr][kt] = lsum;
    __syncthreads();

    if (kt >= 2) {
        float* dst = red[kt - 2];
        #pragma unroll
        for (int nt = 0; nt < 8; ++nt)
            #pragma unroll
            for (int r = 0; r < 4; ++r)
                dst[(rowg*16 + lg*4 + r)*132 + nt*16 + lr] = acc[nt][r];
    }
    __syncthreads();
    if (kt < 2) {
        const float* s = red[kt];
        #pragma unroll
        for (int nt = 0; nt < 8; ++nt)
            #pragma unroll
            for (int r = 0; r < 4; ++r)
                acc[nt][r] += s[(rowg*16 + lg*4 + r)*132 + nt*16 + lr];
    }
    __syncthreads();
    if (kt == 1) {
        float* dst = red[0];
        #pragma unroll
        for (int nt = 0; nt < 8; ++nt)
            #pragma unroll
            for (int r = 0; r < 4; ++r)
                dst[(rowg*16 + lg*4 + r)*132 + nt*16 + lr] = acc[nt][r];
    }
    __syncthreads();
    if (kt == 0) {
        float rv[4];
        #pragma unroll
        for (int r = 0; r < 4; ++r) {
            const float* lsr = ls[rowg*16 + lg*4 + r];
            float tot = lsr[0] + lsr[1] + lsr[2] + lsr[3];
            rv[r] = tot > 0.f ? 1.f / tot : 0.f;
        }
        #pragma unroll
        for (int nt = 0; nt < 8; ++nt)
            #pragma unroll
            for (int r = 0; r < 4; ++r) {
                float v = acc[nt][r] + red[0][(rowg*16 + lg*4 + r)*132 + nt*16 + lr];
                v *= rv[r];
                v = v > 0.f ? v : expm1f(v);
                int row = i0 + rowg*16 + lg*4 + r;
                out[(size_t)(b*NN + row)*NF + f0 + nt*16 + lr] = v;
            }
    }
}

extern "C" void kernel_launch(void* const* d_in, const int* in_sizes, int n_in,
                              void* d_out, int out_size, void* d_ws, size_t ws_size,
                              hipStream_t stream) {
    const float* x   = (const float*)d_in[0];
    const int*   adj = (const int*)d_in[1];
    const float* W   = (const float*)d_in[2];
    const float* a   = (const float*)d_in[3];
    float* out = (float*)d_out;
    char* ws = (char*)d_ws;

    short* WT       = (short*)(ws);                   // 128 KB
    short* hT       = (short*)(ws + 0x20000);         // 4 MB
    float* fs2      = (float*)(ws + 0x420000);        // 32 KB
    float* fd2      = (float*)(ws + 0x428000);        // 32 KB
    unsigned* maxfd = (unsigned*)(ws + 0x430000);     // 16 B
    unsigned short* adjB16 = (unsigned short*)(ws + 0x440000); // 2 MB

    pack_kernel<<<4096 + (NF*NF)/256 + 1, 256, 0, stream>>>(adj, adjB16, W, WT, maxfd);
    h_kernel<<<(NB*NN)/16, 256, 0, stream>>>(x, WT, a, hT, fs2, fd2, maxfd);
    gat_fused<<<NB*128, 512, 0, stream>>>(hT, (const unsigned char*)adjB16,
                                          fs2, fd2, maxfd, out);
}

// Round 10
// 75.019 us; speedup vs baseline: 1.4580x; 1.4580x over previous
//
#include <hip/hip_runtime.h>
#include <hip/hip_bf16.h>

#define NB 4
#define NN 2048
#define NF 256
#define LOG2E 1.4426950408889634f

using bf16x8 = __attribute__((ext_vector_type(8))) short;
using f32x4  = __attribute__((ext_vector_type(4))) float;

__device__ __forceinline__ short f2bf(float f) {
    unsigned u = __float_as_uint(f);
    u += 0x7fffu + ((u >> 16) & 1u);   // RNE, finite inputs only
    return (short)(u >> 16);
}
__device__ __forceinline__ unsigned enc_ord(float f) {
    unsigned u = __float_as_uint(f);
    return (u & 0x80000000u) ? ~u : (u | 0x80000000u);
}
__device__ __forceinline__ float dec_ord(unsigned u) {
    unsigned i = (u & 0x80000000u) ? (u & 0x7fffffffu) : ~u;
    return __uint_as_float(i);
}
__device__ __forceinline__ void gll16(const void* g, void* l) {
    __builtin_amdgcn_global_load_lds(
        (const __attribute__((address_space(1))) unsigned int*)g,
        (__attribute__((address_space(3))) unsigned int*)l, 16, 0, 0);
}

// ---- pack: adj -> 1-bit mask, W->W^T bf16, maxfd init (R7-proven) ----
__global__ __launch_bounds__(256) void pack_kernel(
    const int* __restrict__ adj, unsigned short* __restrict__ adjB16,
    const float* __restrict__ W, short* __restrict__ WT, unsigned* __restrict__ maxfd)
{
    const int blk = blockIdx.x, tid = threadIdx.x;
    if (blk < 4096) {                       // 1M threads x 16 ints (64 B each)
        const int g = blk*256 + tid;
        const int4* p = (const int4*)(adj + (size_t)g*16);
        int4 v0 = p[0], v1 = p[1], v2 = p[2], v3 = p[3];
        unsigned m = 0;
        m |= (v0.x>0)<<0;  m |= (v0.y>0)<<1;  m |= (v0.z>0)<<2;  m |= (v0.w>0)<<3;
        m |= (v1.x>0)<<4;  m |= (v1.y>0)<<5;  m |= (v1.z>0)<<6;  m |= (v1.w>0)<<7;
        m |= (v2.x>0)<<8;  m |= (v2.y>0)<<9;  m |= (v2.z>0)<<10; m |= (v2.w>0)<<11;
        m |= (v3.x>0)<<12; m |= (v3.y>0)<<13; m |= (v3.z>0)<<14; m |= (v3.w>0)<<15;
        adjB16[g] = (unsigned short)m;
    } else if (blk < 4096 + (NF*NF)/256) {
        int t = (blk - 4096)*256 + tid;
        WT[t] = f2bf(W[(t & 255)*NF + (t >> 8)]);   // WT[g][f] = W[f][g]
    } else if (tid < NB) {
        maxfd[tid] = 0u;
    }
}

// ---- h = x@W (bf16 MFMA, K-pipelined); hT[b][g][i], fs2/fd2 (x LOG2E), maxfd ----
__global__ __launch_bounds__(256,4) void h_kernel(
    const float* __restrict__ x, const short* __restrict__ WT, const float* __restrict__ a,
    short* __restrict__ hT, float* __restrict__ fs2, float* __restrict__ fd2,
    unsigned* __restrict__ maxfd)
{
    __shared__ float fs_l[16], fd_l[16];
    const int w  = threadIdx.x >> 6;
    const int l  = threadIdx.x & 63;
    const int lr = l & 15, lg = l >> 4;
    const int b  = blockIdx.x >> 7;
    const int ib = (blockIdx.x & 127) * 16;

    if (threadIdx.x < 16) { fs_l[threadIdx.x] = 0.f; fd_l[threadIdx.x] = 0.f; }
    __syncthreads();

    f32x4 acc[4];
    #pragma unroll
    for (int t = 0; t < 4; t++) acc[t] = (f32x4){0.f,0.f,0.f,0.f};

    const float* xrow = x + (size_t)(b*NN + ib + lr) * NF + 8*lg;
    const short* wtp  = WT + (size_t)(w*64 + lr) * NF + 8*lg;

    float4 xa[2][2]; bf16x8 bfr[2][4];
    xa[0][0] = *(const float4*)(xrow);
    xa[0][1] = *(const float4*)(xrow + 4);
    #pragma unroll
    for (int nt = 0; nt < 4; nt++) bfr[0][nt] = *(const bf16x8*)(wtp + nt*16*NF);

    #pragma unroll
    for (int ks = 0; ks < 8; ks++) {
        const int cur = ks & 1;
        if (ks < 7) {
            const int nxt = cur ^ 1;
            xa[nxt][0] = *(const float4*)(xrow + (ks+1)*32);
            xa[nxt][1] = *(const float4*)(xrow + (ks+1)*32 + 4);
            #pragma unroll
            for (int nt = 0; nt < 4; nt++)
                bfr[nxt][nt] = *(const bf16x8*)(wtp + nt*16*NF + (ks+1)*32);
        }
        bf16x8 af;
        af[0]=f2bf(xa[cur][0].x); af[1]=f2bf(xa[cur][0].y);
        af[2]=f2bf(xa[cur][0].z); af[3]=f2bf(xa[cur][0].w);
        af[4]=f2bf(xa[cur][1].x); af[5]=f2bf(xa[cur][1].y);
        af[6]=f2bf(xa[cur][1].z); af[7]=f2bf(xa[cur][1].w);
        #pragma unroll
        for (int nt = 0; nt < 4; nt++)
            acc[nt] = __builtin_amdgcn_mfma_f32_16x16x32_bf16(af, bfr[cur][nt], acc[nt], 0, 0, 0);
    }

    float fsv[4] = {0,0,0,0}, fdv[4] = {0,0,0,0};
    #pragma unroll
    for (int nt = 0; nt < 4; nt++) {
        int g = w*64 + nt*16 + lr;
        float as = a[g], ad = a[NF + g];
        short4 hv;
        hv.x = f2bf(acc[nt][0]); hv.y = f2bf(acc[nt][1]);
        hv.z = f2bf(acc[nt][2]); hv.w = f2bf(acc[nt][3]);
        *(short4*)(hT + ((size_t)(b*NF + g))*NN + ib + lg*4) = hv;
        #pragma unroll
        for (int r = 0; r < 4; r++) { fsv[r] += acc[nt][r]*as; fdv[r] += acc[nt][r]*ad; }
    }
    #pragma unroll
    for (int mask = 1; mask < 16; mask <<= 1) {
        #pragma unroll
        for (int r = 0; r < 4; r++) {
            fsv[r] += __shfl_xor(fsv[r], mask);
            fdv[r] += __shfl_xor(fdv[r], mask);
        }
    }
    if (lr == 0) {
        #pragma unroll
        for (int r = 0; r < 4; r++) {
            atomicAdd(&fs_l[lg*4 + r], fsv[r]);
            atomicAdd(&fd_l[lg*4 + r], fdv[r]);
        }
    }
    __syncthreads();
    if (threadIdx.x < 16) {
        float fsu = fs_l[threadIdx.x] * LOG2E;
        float fdu = fd_l[threadIdx.x] * LOG2E;
        fs2[b*NN + ib + threadIdx.x] = fsu;
        fd2[b*NN + ib + threadIdx.x] = fdu;
        float wm = fdu;
        #pragma unroll
        for (int m = 1; m < 16; m <<= 1) wm = fmaxf(wm, __shfl_xor(wm, m));
        if (threadIdx.x == 0) atomicMax(maxfd + b, enc_ord(wm));
    }
}

// ---- fused: masked softmax + att@h + elu ----
// grid 1024 = 4b x 64 itile(32 rows) x 4 fq(64 f); 256 thr = 4 waves = 4 kt.
// Each wave: 32 rows (2 A-frags in-register P) x 4 f-tiles x 32-j kt slice
// => 8 MFMA per 4 ds_read (halved LDS load vs R7). 16 steps BK=128.
// 3-slot LDS (16KB each), single vmcnt(8)+barrier fence per step (R7 pattern).
__global__ __launch_bounds__(256,3) void gat_fused(
    const short* __restrict__ hT, const unsigned char* __restrict__ adjB,
    const float* __restrict__ fs2, const float* __restrict__ fd2,
    const unsigned* __restrict__ maxfd, float* __restrict__ out)
{
    __shared__ __align__(16) char smem[49664];   // 3x16384 staging + 512B ls
    float* ls = (float*)(smem + 49152);          // [32][4]

    const int tid = threadIdx.x;
    const int kt = tid >> 6, l = tid & 63, lr = l & 15, lg = l >> 4;
    const int blk = blockIdx.x;
    const int b = blk >> 8, rest = blk & 255;
    const int itile = rest >> 2, fq = rest & 3;
    const int i0 = itile * 32, f0 = fq * 64;

    const short* hTb = hT + ((size_t)b * NF + f0) * NN;

    // staging sources: 4 chunks/thread, inverse-XOR (linear gll dst + XOR read)
    const short* sbp[4];
    #pragma unroll
    for (int i = 0; i < 4; ++i) {
        int s = tid + 256*i;                     // chunk id 0..1023
        int r = s >> 4, pc = s & 15;
        int c = pc ^ (r & 15);
        sbp[i] = hTb + (size_t)r * NN + c*8;
    }

    // per-row softmax constants (rows i0+lr and i0+16+lr), log2-scaled
    const float mx2 = dec_ord(maxfd[b]);
    const int gi0 = b*NN + i0 + lr;
    const float fsa = fs2[gi0], fsb = fs2[gi0 + 16];
    const float M0 = fmaxf(fsa + mx2, 0.f), M1 = fmaxf(fsb + mx2, 0.f);
    const float fsM0 = fsa - M0, nM0 = -M0;
    const float fsM1 = fsb - M1, nM1 = -M1;

    const unsigned char* ar0 = adjB + (size_t)gi0 * (NN/8) + kt*4 + lg;
    const unsigned char* ar1 = ar0 + 16*(NN/8);
    const float* fdp = fd2 + b*NN + kt*32 + lg*8;

    const int boff = lr*256 + (((kt*4 + lg) ^ lr) << 4);   // + nt*4096 per f-tile

    f32x4 acc[2][4];
    #pragma unroll
    for (int i = 0; i < 2; ++i)
        #pragma unroll
        for (int j = 0; j < 4; ++j) acc[i][j] = (f32x4){0.f,0.f,0.f,0.f};
    float ls0a = 0.f, ls0b = 0.f, ls1a = 0.f, ls1b = 0.f;

    auto STAGE = [&](int t, int slot) {          // 4 gll/thread, 16KB tile
        char* dst = smem + slot * 16384;
        #pragma unroll
        for (int i = 0; i < 4; ++i)
            gll16(sbp[i] + t*128, dst + (tid + 256*i)*16);
    };
    auto LOADP = [&](int t, unsigned& m0, unsigned& m1, f32x4& fa, f32x4& fb) {
        m0 = ar0[t*16]; m1 = ar1[t*16];
        fa = *(const f32x4*)(fdp + t*128);
        fb = *(const f32x4*)(fdp + t*128 + 4);
    };
    auto BODY = [&](int slot, unsigned m0, unsigned m1, const f32x4& fa, const f32x4& fb) {
        const char* sb = smem + slot * 16384;
        bf16x8 b0 = *(const bf16x8*)(sb + boff);
        bf16x8 b1 = *(const bf16x8*)(sb + boff + 4096);
        bf16x8 b2 = *(const bf16x8*)(sb + boff + 8192);
        bf16x8 b3 = *(const bf16x8*)(sb + boff + 12288);
        float fdv[8] = {fa[0],fa[1],fa[2],fa[3],fb[0],fb[1],fb[2],fb[3]};
        float p0[8], p1[8];
        #pragma unroll
        for (int e = 0; e < 8; ++e) {
            float v0 = __builtin_amdgcn_exp2f(fmaxf(fsM0 + fdv[e], nM0));
            float v1 = __builtin_amdgcn_exp2f(fmaxf(fsM1 + fdv[e], nM1));
            v0 = (m0 & (1u << e)) ? v0 : 0.f;
            v1 = (m1 & (1u << e)) ? v1 : 0.f;
            if (e < 4) { ls0a += v0; ls1a += v1; } else { ls0b += v0; ls1b += v1; }
            p0[e] = v0;  p1[e] = v1;
        }
        union { bf16x8 v; unsigned u[4]; } a0u, a1u;
        #pragma unroll
        for (int d = 0; d < 4; ++d) {
            asm("v_cvt_pk_bf16_f32 %0, %1, %2" : "=v"(a0u.u[d]) : "v"(p0[2*d]), "v"(p0[2*d+1]));
            asm("v_cvt_pk_bf16_f32 %0, %1, %2" : "=v"(a1u.u[d]) : "v"(p1[2*d]), "v"(p1[2*d+1]));
        }
        acc[0][0] = __builtin_amdgcn_mfma_f32_16x16x32_bf16(a0u.v, b0, acc[0][0], 0, 0, 0);
        acc[1][0] = __builtin_amdgcn_mfma_f32_16x16x32_bf16(a1u.v, b0, acc[1][0], 0, 0, 0);
        acc[0][1] = __builtin_amdgcn_mfma_f32_16x16x32_bf16(a0u.v, b1, acc[0][1], 0, 0, 0);
        acc[1][1] = __builtin_amdgcn_mfma_f32_16x16x32_bf16(a1u.v, b1, acc[1][1], 0, 0, 0);
        acc[0][2] = __builtin_amdgcn_mfma_f32_16x16x32_bf16(a0u.v, b2, acc[0][2], 0, 0, 0);
        acc[1][2] = __builtin_amdgcn_mfma_f32_16x16x32_bf16(a1u.v, b2, acc[1][2], 0, 0, 0);
        acc[0][3] = __builtin_amdgcn_mfma_f32_16x16x32_bf16(a0u.v, b3, acc[0][3], 0, 0, 0);
        acc[1][3] = __builtin_amdgcn_mfma_f32_16x16x32_bf16(a1u.v, b3, acc[1][3], 0, 0, 0);
    };
    #define FENCE8 do { __builtin_amdgcn_sched_barrier(0); \
        asm volatile("s_waitcnt vmcnt(8)" ::: "memory"); \
        __builtin_amdgcn_s_barrier(); \
        __builtin_amdgcn_sched_barrier(0); } while (0)
    #define FENCE0 do { __builtin_amdgcn_sched_barrier(0); \
        asm volatile("s_waitcnt vmcnt(0)" ::: "memory"); \
        __builtin_amdgcn_s_barrier(); \
        __builtin_amdgcn_sched_barrier(0); } while (0)

    unsigned mA0, mA1, mB0, mB1;
    f32x4 faA, fbA, faB, fbB;

    // prologue: S0,P0,S1,P1 issued; wait S0+P0 (keep 8 newest in flight)
    STAGE(0, 0); LOADP(0, mA0, mA1, faA, fbA);
    STAGE(1, 1); LOADP(1, mB0, mB1, faB, fbB);
    FENCE8;

    for (int t2 = 0; t2 < 16; t2 += 2) {
        // step t2 (set A, slot t2%3)
        if (t2 + 2 < 16) {
            STAGE(t2 + 2, (t2 + 2) % 3);
            BODY(t2 % 3, mA0, mA1, faA, fbA);
            LOADP(t2 + 2, mA0, mA1, faA, fbA);
            FENCE8;
        } else {
            BODY(t2 % 3, mA0, mA1, faA, fbA);
            FENCE0;                           // drain STAGE(15) before last body
        }
        // step t2+1 (set B, slot (t2+1)%3)
        if (t2 + 3 < 16) {
            STAGE(t2 + 3, (t2 + 3) % 3);
            BODY((t2 + 1) % 3, mB0, mB1, faB, fbB);
            LOADP(t2 + 3, mB0, mB1, faB, fbB);
            FENCE8;
        } else {
            BODY((t2 + 1) % 3, mB0, mB1, faB, fbB);
        }
    }

    // ---- epilogue: row sums + kt-tree + elu + store ----
    float lsum0 = ls0a + ls0b, lsum1 = ls1a + ls1b;
    lsum0 += __shfl_xor(lsum0, 16); lsum0 += __shfl_xor(lsum0, 32);
    lsum1 += __shfl_xor(lsum1, 16); lsum1 += __shfl_xor(lsum1, 32);
    if (l < 16) {
        ls[lr*4 + kt]        = lsum0;
        ls[(16 + lr)*4 + kt] = lsum1;
    }
    __syncthreads();

    float* red  = (float*)smem;                  // 32x68 f32 = 8.5KB (alias staging)
    float* red2 = (float*)(smem + 16384);
    if (kt >= 2) {
        float* dst = (kt == 2) ? red : red2;
        #pragma unroll
        for (int mt = 0; mt < 2; ++mt)
            #pragma unroll
            for (int nt = 0; nt < 4; ++nt)
                #pragma unroll
                for (int r = 0; r < 4; ++r)
                    dst[(mt*16 + lg*4 + r)*68 + nt*16 + lr] = acc[mt][nt][r];
    }
    __syncthreads();
    if (kt < 2) {
        const float* srcp = (kt == 0) ? red : red2;
        #pragma unroll
        for (int mt = 0; mt < 2; ++mt)
            #pragma unroll
            for (int nt = 0; nt < 4; ++nt)
                #pragma unroll
                for (int r = 0; r < 4; ++r)
                    acc[mt][nt][r] += srcp[(mt*16 + lg*4 + r)*68 + nt*16 + lr];
    }
    __syncthreads();
    if (kt == 1) {
        #pragma unroll
        for (int mt = 0; mt < 2; ++mt)
            #pragma unroll
            for (int nt = 0; nt < 4; ++nt)
                #pragma unroll
                for (int r = 0; r < 4; ++r)
                    red[(mt*16 + lg*4 + r)*68 + nt*16 + lr] = acc[mt][nt][r];
    }
    __syncthreads();
    if (kt == 0) {
        float rv[2][4];
        #pragma unroll
        for (int mt = 0; mt < 2; ++mt)
            #pragma unroll
            for (int r = 0; r < 4; ++r) {
                int row = mt*16 + lg*4 + r;
                float tot = ls[row*4] + ls[row*4+1] + ls[row*4+2] + ls[row*4+3];
                rv[mt][r] = tot > 0.f ? 1.f / tot : 0.f;
            }
        #pragma unroll
        for (int mt = 0; mt < 2; ++mt)
            #pragma unroll
            for (int nt = 0; nt < 4; ++nt)
                #pragma unroll
                for (int r = 0; r < 4; ++r) {
                    float v = acc[mt][nt][r]
                            + red[(mt*16 + lg*4 + r)*68 + nt*16 + lr];
                    v *= rv[mt][r];
                    v = v > 0.f ? v : expm1f(v);
                    int row = i0 + mt*16 + lg*4 + r;
                    out[(size_t)(b*NN + row)*NF + f0 + nt*16 + lr] = v;
                }
    }
    #undef FENCE8
    #undef FENCE0
}

extern "C" void kernel_launch(void* const* d_in, const int* in_sizes, int n_in,
                              void* d_out, int out_size, void* d_ws, size_t ws_size,
                              hipStream_t stream) {
    const float* x   = (const float*)d_in[0];
    const int*   adj = (const int*)d_in[1];
    const float* W   = (const float*)d_in[2];
    const float* a   = (const float*)d_in[3];
    float* out = (float*)d_out;
    char* ws = (char*)d_ws;

    short* WT       = (short*)(ws);                   // 128 KB
    short* hT       = (short*)(ws + 0x20000);         // 4 MB
    float* fs2      = (float*)(ws + 0x420000);        // 32 KB
    float* fd2      = (float*)(ws + 0x428000);        // 32 KB
    unsigned* maxfd = (unsigned*)(ws + 0x430000);     // 16 B
    unsigned short* adjB16 = (unsigned short*)(ws + 0x440000); // 2 MB

    pack_kernel<<<4096 + (NF*NF)/256 + 1, 256, 0, stream>>>(adj, adjB16, W, WT, maxfd);
    h_kernel<<<(NB*NN)/16, 256, 0, stream>>>(x, WT, a, hT, fs2, fd2, maxfd);
    gat_fused<<<NB*256, 256, 0, stream>>>(hT, (const unsigned char*)adjB16,
                                          fs2, fd2, maxfd, out);
}

// Round 11
// 74.144 us; speedup vs baseline: 1.4752x; 1.0118x over previous
//
#include <hip/hip_runtime.h>
#include <hip/hip_bf16.h>

#define NB 4
#define NN 2048
#define NF 256
#define LOG2E 1.4426950408889634f

using bf16x8 = __attribute__((ext_vector_type(8))) short;
using f32x4  = __attribute__((ext_vector_type(4))) float;

__device__ __forceinline__ short f2bf(float f) {
    unsigned u = __float_as_uint(f);
    u += 0x7fffu + ((u >> 16) & 1u);   // RNE, finite inputs only
    return (short)(u >> 16);
}
__device__ __forceinline__ unsigned enc_ord(float f) {
    unsigned u = __float_as_uint(f);
    return (u & 0x80000000u) ? ~u : (u | 0x80000000u);
}
__device__ __forceinline__ float dec_ord(unsigned u) {
    unsigned i = (u & 0x80000000u) ? (u & 0x7fffffffu) : ~u;
    return __uint_as_float(i);
}
__device__ __forceinline__ void gll16(const void* g, void* l) {
    __builtin_amdgcn_global_load_lds(
        (const __attribute__((address_space(1))) unsigned int*)g,
        (__attribute__((address_space(3))) unsigned int*)l, 16, 0, 0);
}

// ---- prep: W->W^T bf16, maxfd init (tiny) ----
__global__ __launch_bounds__(256) void prep_kernel(
    const float* __restrict__ W, short* __restrict__ WT, unsigned* __restrict__ maxfd)
{
    const int blk = blockIdx.x, tid = threadIdx.x;
    if (blk < (NF*NF)/256) {
        int t = blk*256 + tid;
        WT[t] = f2bf(W[(t & 255)*NF + (t >> 8)]);   // WT[g][f] = W[f][g]
    } else if (tid < NB) {
        maxfd[tid] = 0u;
    }
}

// ---- h = x@W (bf16 MFMA, K-pipelined); hT[b][g][i], fs2/fd2 (x LOG2E), maxfd ----
__global__ __launch_bounds__(256,4) void h_kernel(
    const float* __restrict__ x, const short* __restrict__ WT, const float* __restrict__ a,
    short* __restrict__ hT, float* __restrict__ fs2, float* __restrict__ fd2,
    unsigned* __restrict__ maxfd)
{
    __shared__ float fs_l[16], fd_l[16];
    const int w  = threadIdx.x >> 6;
    const int l  = threadIdx.x & 63;
    const int lr = l & 15, lg = l >> 4;
    const int b  = blockIdx.x >> 7;
    const int ib = (blockIdx.x & 127) * 16;

    if (threadIdx.x < 16) { fs_l[threadIdx.x] = 0.f; fd_l[threadIdx.x] = 0.f; }
    __syncthreads();

    f32x4 acc[4];
    #pragma unroll
    for (int t = 0; t < 4; t++) acc[t] = (f32x4){0.f,0.f,0.f,0.f};

    const float* xrow = x + (size_t)(b*NN + ib + lr) * NF + 8*lg;
    const short* wtp  = WT + (size_t)(w*64 + lr) * NF + 8*lg;

    float4 xa[2][2]; bf16x8 bfr[2][4];
    xa[0][0] = *(const float4*)(xrow);
    xa[0][1] = *(const float4*)(xrow + 4);
    #pragma unroll
    for (int nt = 0; nt < 4; nt++) bfr[0][nt] = *(const bf16x8*)(wtp + nt*16*NF);

    #pragma unroll
    for (int ks = 0; ks < 8; ks++) {
        const int cur = ks & 1;
        if (ks < 7) {
            const int nxt = cur ^ 1;
            xa[nxt][0] = *(const float4*)(xrow + (ks+1)*32);
            xa[nxt][1] = *(const float4*)(xrow + (ks+1)*32 + 4);
            #pragma unroll
            for (int nt = 0; nt < 4; nt++)
                bfr[nxt][nt] = *(const bf16x8*)(wtp + nt*16*NF + (ks+1)*32);
        }
        bf16x8 af;
        af[0]=f2bf(xa[cur][0].x); af[1]=f2bf(xa[cur][0].y);
        af[2]=f2bf(xa[cur][0].z); af[3]=f2bf(xa[cur][0].w);
        af[4]=f2bf(xa[cur][1].x); af[5]=f2bf(xa[cur][1].y);
        af[6]=f2bf(xa[cur][1].z); af[7]=f2bf(xa[cur][1].w);
        #pragma unroll
        for (int nt = 0; nt < 4; nt++)
            acc[nt] = __builtin_amdgcn_mfma_f32_16x16x32_bf16(af, bfr[cur][nt], acc[nt], 0, 0, 0);
    }

    float fsv[4] = {0,0,0,0}, fdv[4] = {0,0,0,0};
    #pragma unroll
    for (int nt = 0; nt < 4; nt++) {
        int g = w*64 + nt*16 + lr;
        float as = a[g], ad = a[NF + g];
        short4 hv;
        hv.x = f2bf(acc[nt][0]); hv.y = f2bf(acc[nt][1]);
        hv.z = f2bf(acc[nt][2]); hv.w = f2bf(acc[nt][3]);
        *(short4*)(hT + ((size_t)(b*NF + g))*NN + ib + lg*4) = hv;
        #pragma unroll
        for (int r = 0; r < 4; r++) { fsv[r] += acc[nt][r]*as; fdv[r] += acc[nt][r]*ad; }
    }
    #pragma unroll
    for (int mask = 1; mask < 16; mask <<= 1) {
        #pragma unroll
        for (int r = 0; r < 4; r++) {
            fsv[r] += __shfl_xor(fsv[r], mask);
            fdv[r] += __shfl_xor(fdv[r], mask);
        }
    }
    if (lr == 0) {
        #pragma unroll
        for (int r = 0; r < 4; r++) {
            atomicAdd(&fs_l[lg*4 + r], fsv[r]);
            atomicAdd(&fd_l[lg*4 + r], fdv[r]);
        }
    }
    __syncthreads();
    if (threadIdx.x < 16) {
        float fsu = fs_l[threadIdx.x] * LOG2E;
        float fdu = fd_l[threadIdx.x] * LOG2E;
        fs2[b*NN + ib + threadIdx.x] = fsu;
        fd2[b*NN + ib + threadIdx.x] = fdu;
        float wm = fdu;
        #pragma unroll
        for (int m = 1; m < 16; m <<= 1) wm = fmaxf(wm, __shfl_xor(wm, m));
        if (threadIdx.x == 0) atomicMax(maxfd + b, enc_ord(wm));
    }
}

// ---- fused: masked softmax + att@h + elu ----
// grid 512 = 4b x 64 itile(32 rows) x 2 fh(128 f); 256 thr = 4 kt waves.
// Wave: 32 rows (2 A-frags) x 8 f-tiles x 32-j kt slice -> 16+2 MFMA / 8 ds_read.
// Exp computed once per (i,j) per fh (x2 total, was x4). adj read DIRECTLY
// (no pack pass): 2-step-ahead int4 prefetch covers HBM latency.
// Row sums via ones-B MFMA (no VALU adds, no epilogue shuffles).
// 2 slots x 32KB, ONE vmcnt(6)+barrier fence per step.
__global__ __launch_bounds__(256,2) void gat_fused(
    const short* __restrict__ hT, const int* __restrict__ adj,
    const float* __restrict__ fs2, const float* __restrict__ fd2,
    const unsigned* __restrict__ maxfd, float* __restrict__ out)
{
    __shared__ __align__(16) char smem[65536];   // 2 x 32KB staging (epilogue aliases)

    const int tid = threadIdx.x;
    const int kt = tid >> 6, l = tid & 63, lr = l & 15, lg = l >> 4;
    const int blk = blockIdx.x;
    const int b = blk >> 7, rest = blk & 127;
    const int itile = rest >> 1, fh = rest & 1;
    const int i0 = itile * 32, f0 = fh * 128;

    const short* hTb = hT + ((size_t)b * NF + f0) * NN;

    // staging sources: 8 chunks/thread, inverse-XOR (linear gll dst + XOR read)
    const short* sbp[8];
    #pragma unroll
    for (int i = 0; i < 8; ++i) {
        int s = tid + 256*i;                     // chunk id 0..2047
        int r = s >> 4, pc = s & 15;
        int c = pc ^ (r & 15);
        sbp[i] = hTb + (size_t)r * NN + c*8;
    }

    // per-row softmax constants (rows i0+lr and i0+16+lr), log2-scaled
    const float mx2 = dec_ord(maxfd[b]);
    const int gi0 = b*NN + i0 + lr;
    const float fsa = fs2[gi0], fsb = fs2[gi0 + 16];
    const float M0 = fmaxf(fsa + mx2, 0.f), M1 = fmaxf(fsb + mx2, 0.f);
    const float fsM0 = fsa - M0, nM0 = -M0;
    const float fsM1 = fsb - M1, nM1 = -M1;

    const int* ar0 = adj + (size_t)gi0 * NN + kt*32 + lg*8;
    const int* ar1 = ar0 + (size_t)16 * NN;
    const float* fdp = fd2 + b*NN + kt*32 + lg*8;

    const int boff = lr*256 + (((kt*4 + lg) ^ lr) << 4);   // + nt*4096 per f-tile

    f32x4 acc[2][8];
    #pragma unroll
    for (int i = 0; i < 2; ++i)
        #pragma unroll
        for (int j = 0; j < 8; ++j) acc[i][j] = (f32x4){0.f,0.f,0.f,0.f};
    f32x4 acc1[2];
    acc1[0] = (f32x4){0.f,0.f,0.f,0.f};
    acc1[1] = (f32x4){0.f,0.f,0.f,0.f};

    bf16x8 bONE;
    #pragma unroll
    for (int d = 0; d < 8; ++d) bONE[d] = (short)0x3F80;   // bf16 1.0

    auto STAGE = [&](int t, int slot) {          // 8 gll/thread, 32KB tile
        char* dst = smem + slot * 32768;
        #pragma unroll
        for (int i = 0; i < 8; ++i)
            gll16(sbp[i] + t*128, dst + (tid + 256*i)*16);
    };
    auto LOADP = [&](int t, int4& a0l, int4& a0h, int4& a1l, int4& a1h,
                     f32x4& fa, f32x4& fb) {
        const int base = t << 7;
        a0l = *(const int4*)(ar0 + base);
        a0h = *(const int4*)(ar0 + base + 4);
        a1l = *(const int4*)(ar1 + base);
        a1h = *(const int4*)(ar1 + base + 4);
        fa  = *(const f32x4*)(fdp + base);
        fb  = *(const f32x4*)(fdp + base + 4);
    };
    auto BODY = [&](int slot, const int4& a0l, const int4& a0h,
                    const int4& a1l, const int4& a1h,
                    const f32x4& fa, const f32x4& fb) {
        const char* sb = smem + slot * 32768;
        bf16x8 B[8];
        #pragma unroll
        for (int nt = 0; nt < 8; ++nt)
            B[nt] = *(const bf16x8*)(sb + boff + nt*4096);
        const float fdv[8] = {fa[0],fa[1],fa[2],fa[3],fb[0],fb[1],fb[2],fb[3]};
        const int a0v[8] = {a0l.x,a0l.y,a0l.z,a0l.w,a0h.x,a0h.y,a0h.z,a0h.w};
        const int a1v[8] = {a1l.x,a1l.y,a1l.z,a1l.w,a1h.x,a1h.y,a1h.z,a1h.w};
        float p0[8], p1[8];
        #pragma unroll
        for (int e = 0; e < 8; ++e) {
            float v0 = __builtin_amdgcn_exp2f(fmaxf(fsM0 + fdv[e], nM0));
            float v1 = __builtin_amdgcn_exp2f(fmaxf(fsM1 + fdv[e], nM1));
            p0[e] = (a0v[e] > 0) ? v0 : 0.f;
            p1[e] = (a1v[e] > 0) ? v1 : 0.f;
        }
        union { bf16x8 v; unsigned u[4]; } a0u, a1u;
        #pragma unroll
        for (int d = 0; d < 4; ++d) {
            asm("v_cvt_pk_bf16_f32 %0, %1, %2" : "=v"(a0u.u[d]) : "v"(p0[2*d]), "v"(p0[2*d+1]));
            asm("v_cvt_pk_bf16_f32 %0, %1, %2" : "=v"(a1u.u[d]) : "v"(p1[2*d]), "v"(p1[2*d+1]));
        }
        #pragma unroll
        for (int nt = 0; nt < 8; ++nt) {
            acc[0][nt] = __builtin_amdgcn_mfma_f32_16x16x32_bf16(a0u.v, B[nt], acc[0][nt], 0, 0, 0);
            acc[1][nt] = __builtin_amdgcn_mfma_f32_16x16x32_bf16(a1u.v, B[nt], acc[1][nt], 0, 0, 0);
        }
        acc1[0] = __builtin_amdgcn_mfma_f32_16x16x32_bf16(a0u.v, bONE, acc1[0], 0, 0, 0);
        acc1[1] = __builtin_amdgcn_mfma_f32_16x16x32_bf16(a1u.v, bONE, acc1[1], 0, 0, 0);
    };
    #define FENCE6 do { __builtin_amdgcn_sched_barrier(0); \
        asm volatile("s_waitcnt vmcnt(6)" ::: "memory"); \
        __builtin_amdgcn_s_barrier(); \
        __builtin_amdgcn_sched_barrier(0); } while (0)
    #define FENCE0 do { __builtin_amdgcn_sched_barrier(0); \
        asm volatile("s_waitcnt vmcnt(0)" ::: "memory"); \
        __builtin_amdgcn_s_barrier(); \
        __builtin_amdgcn_sched_barrier(0); } while (0)

    int4 Aa0l, Aa0h, Aa1l, Aa1h; f32x4 Afa, Afb;   // prefetch set A (even steps)
    int4 Ba0l, Ba0h, Ba1l, Ba1h; f32x4 Bfa, Bfb;   // prefetch set B (odd steps)

    // prologue: stage slot0; prefetch steps 0,1 (2-ahead covers HBM latency)
    STAGE(0, 0);
    LOADP(0, Aa0l, Aa0h, Aa1l, Aa1h, Afa, Afb);
    LOADP(1, Ba0l, Ba0h, Ba1l, Ba1h, Bfa, Bfb);
    FENCE6;                                   // waits STAGE(0)+LOADP(0); leaves LOADP(1)

    for (int t2 = 0; t2 < 16; t2 += 2) {
        // step t2 (set A, slot 0)
        STAGE(t2 + 1, 1);
        BODY(0, Aa0l, Aa0h, Aa1l, Aa1h, Afa, Afb);
        if (t2 + 2 < 16) {
            LOADP(t2 + 2, Aa0l, Aa0h, Aa1l, Aa1h, Afa, Afb);
            FENCE6;                           // waits STAGE(t2+1); leaves LOADP(t2+2)
        } else {
            FENCE0;                           // tail: drain STAGE(15)
        }
        // step t2+1 (set B, slot 1)
        if (t2 + 2 < 16) STAGE(t2 + 2, 0);
        BODY(1, Ba0l, Ba0h, Ba1l, Ba1h, Bfa, Bfb);
        if (t2 + 3 < 16) {
            LOADP(t2 + 3, Ba0l, Ba0h, Ba1l, Ba1h, Bfa, Bfb);
            FENCE6;                           // waits STAGE(t2+2); leaves LOADP(t2+3)
        }
    }
    __syncthreads();                          // all waves out of staging reads

    // ---- epilogue: kt-tree reduction (incl. rowsums at col 128) + elu + store ----
    float* red  = (float*)smem;               // [32][132] = 16.9KB
    float* red2 = (float*)(smem + 17408);
    if (kt >= 2) {
        float* dst = (kt == 2) ? red : red2;
        #pragma unroll
        for (int mt = 0; mt < 2; ++mt) {
            #pragma unroll
            for (int nt = 0; nt < 8; ++nt)
                #pragma unroll
                for (int r = 0; r < 4; ++r)
                    dst[(mt*16 + lg*4 + r)*132 + nt*16 + lr] = acc[mt][nt][r];
            if (lr == 0)
                #pragma unroll
                for (int r = 0; r < 4; ++r)
                    dst[(mt*16 + lg*4 + r)*132 + 128] = acc1[mt][r];
        }
    }
    __syncthreads();
    if (kt < 2) {
        const float* srcp = (kt == 0) ? red : red2;
        #pragma unroll
        for (int mt = 0; mt < 2; ++mt) {
            #pragma unroll
            for (int nt = 0; nt < 8; ++nt)
                #pragma unroll
                for (int r = 0; r < 4; ++r)
                    acc[mt][nt][r] += srcp[(mt*16 + lg*4 + r)*132 + nt*16 + lr];
            #pragma unroll
            for (int r = 0; r < 4; ++r)
                acc1[mt][r] += srcp[(mt*16 + lg*4 + r)*132 + 128];
        }
    }
    __syncthreads();
    if (kt == 1) {
        #pragma unroll
        for (int mt = 0; mt < 2; ++mt) {
            #pragma unroll
            for (int nt = 0; nt < 8; ++nt)
                #pragma unroll
                for (int r = 0; r < 4; ++r)
                    red[(mt*16 + lg*4 + r)*132 + nt*16 + lr] = acc[mt][nt][r];
            if (lr == 0)
                #pragma unroll
                for (int r = 0; r < 4; ++r)
                    red[(mt*16 + lg*4 + r)*132 + 128] = acc1[mt][r];
        }
    }
    __syncthreads();
    if (kt == 0) {
        #pragma unroll
        for (int mt = 0; mt < 2; ++mt) {
            float rv[4];
            #pragma unroll
            for (int r = 0; r < 4; ++r) {
                float tot = acc1[mt][r] + red[(mt*16 + lg*4 + r)*132 + 128];
                rv[r] = tot > 0.f ? 1.f / tot : 0.f;
            }
            #pragma unroll
            for (int nt = 0; nt < 8; ++nt)
                #pragma unroll
                for (int r = 0; r < 4; ++r) {
                    float v = acc[mt][nt][r]
                            + red[(mt*16 + lg*4 + r)*132 + nt*16 + lr];
                    v *= rv[r];
                    v = v > 0.f ? v : expm1f(v);
                    int row = i0 + mt*16 + lg*4 + r;
                    out[(size_t)(b*NN + row)*NF + f0 + nt*16 + lr] = v;
                }
        }
    }
    #undef FENCE6
    #undef FENCE0
}

extern "C" void kernel_launch(void* const* d_in, const int* in_sizes, int n_in,
                              void* d_out, int out_size, void* d_ws, size_t ws_size,
                              hipStream_t stream) {
    const float* x   = (const float*)d_in[0];
    const int*   adj = (const int*)d_in[1];
    const float* W   = (const float*)d_in[2];
    const float* a   = (const float*)d_in[3];
    float* out = (float*)d_out;
    char* ws = (char*)d_ws;

    short* WT       = (short*)(ws);                   // 128 KB
    short* hT       = (short*)(ws + 0x20000);         // 4 MB
    float* fs2      = (float*)(ws + 0x420000);        // 32 KB
    float* fd2      = (float*)(ws + 0x428000);        // 32 KB
    unsigned* maxfd = (unsigned*)(ws + 0x430000);     // 16 B

    prep_kernel<<<(NF*NF)/256 + 1, 256, 0, stream>>>(W, WT, maxfd);
    h_kernel<<<(NB*NN)/16, 256, 0, stream>>>(x, WT, a, hT, fs2, fd2, maxfd);
    gat_fused<<<NB*128, 256, 0, stream>>>(hT, adj, fs2, fd2, maxfd, out);
}